// Round 1
// baseline (896.890 us; speedup 1.0000x reference)
//
#include <hip/hip_runtime.h>
#include <hip/hip_bf16.h>
#include <math.h>

typedef __attribute__((ext_vector_type(8))) short short8;
typedef __attribute__((ext_vector_type(4))) float floatx4;
typedef __attribute__((ext_vector_type(4))) short short4v;

#define D_MODEL 1024
#define N_HEADS 16
#define DK 64
#define D_FF 4096
#define BB 4
#define SS 2048
#define NTOK (BB * SS) /* 8192 */
#define LN_EPS 1e-5f

static __device__ __forceinline__ short f2bf(float f) {
  union { float f; unsigned int u; } v;
  v.f = f;
  unsigned int u = v.u;
  unsigned int r = u + 0x7fffu + ((u >> 16) & 1u); // round-to-nearest-even
  return (short)(r >> 16);
}

// ---------------- LayerNorm: fp32 row -> bf16 row ----------------
__global__ __launch_bounds__(256) void ln_kernel(const float* __restrict__ x,
                                                 const float* __restrict__ g,
                                                 const float* __restrict__ b,
                                                 short* __restrict__ out) {
  int row = blockIdx.x;
  int t = threadIdx.x;
  const float4* rp = (const float4*)(x + (size_t)row * D_MODEL);
  float4 v = rp[t];
  float s = v.x + v.y + v.z + v.w;
  float ss = v.x * v.x + v.y * v.y + v.z * v.z + v.w * v.w;
#pragma unroll
  for (int off = 32; off >= 1; off >>= 1) {
    s += __shfl_xor(s, off, 64);
    ss += __shfl_xor(ss, off, 64);
  }
  __shared__ float red[8];
  int wv = t >> 6, ln = t & 63;
  if (ln == 0) { red[wv] = s; red[wv + 4] = ss; }
  __syncthreads();
  s = red[0] + red[1] + red[2] + red[3];
  ss = red[4] + red[5] + red[6] + red[7];
  float mu = s * (1.0f / D_MODEL);
  float var = ss * (1.0f / D_MODEL) - mu * mu;
  float rstd = rsqrtf(var + LN_EPS);
  float4 gv = ((const float4*)g)[t];
  float4 bv = ((const float4*)b)[t];
  short4v o;
  o.x = f2bf((v.x - mu) * rstd * gv.x + bv.x);
  o.y = f2bf((v.y - mu) * rstd * gv.y + bv.y);
  o.z = f2bf((v.z - mu) * rstd * gv.z + bv.z);
  o.w = f2bf((v.w - mu) * rstd * gv.w + bv.w);
  *(short4v*)(out + (size_t)row * D_MODEL + t * 4) = o;
}

// ------------- Weight convert+transpose: W[K][N] f32 -> Wt[N][K] bf16 -------------
__global__ __launch_bounds__(256) void wconvert(const float* __restrict__ W,
                                                short* __restrict__ Wt, int K, int N) {
  __shared__ float tile[64][65];
  int n0 = blockIdx.x * 64, k0 = blockIdx.y * 64;
  int t = threadIdx.x;
  int c = t & 63, r0 = t >> 6;
#pragma unroll
  for (int i = 0; i < 16; i++) {
    int r = r0 + i * 4;
    tile[r][c] = W[(size_t)(k0 + r) * N + n0 + c];
  }
  __syncthreads();
#pragma unroll
  for (int i = 0; i < 16; i++) {
    int r = r0 + i * 4;
    Wt[(size_t)(n0 + r) * K + k0 + c] = f2bf(tile[c][r]);
  }
}

// ---------------- GEMM: C[M,N] = A[M,K](bf16) x Bt[N,K](bf16) + bias -------------
// MODE 0: +bias -> bf16 out
// MODE 1: +bias +res(fp32) -> fp32 out
// MODE 2: +bias, exact GELU -> bf16 out
#define GLL16(g, l)                                                            \
  __builtin_amdgcn_global_load_lds(                                            \
      (const __attribute__((address_space(1))) void*)(g),                      \
      (__attribute__((address_space(3))) void*)(l), 16, 0, 0)

template <int MODE>
__global__ __launch_bounds__(256) void gemm_bt(const short* __restrict__ A,
                                               const short* __restrict__ Bt,
                                               const float* __restrict__ bias,
                                               const float* __restrict__ res,
                                               float* __restrict__ outf,
                                               short* __restrict__ outb,
                                               int M, int N, int K) {
  __shared__ short As[128 * 32];
  __shared__ short Bs[128 * 32];
  int t = threadIdx.x;
  int w = t >> 6, l = t & 63;
  int m0 = blockIdx.y * 128, n0 = blockIdx.x * 128;
  floatx4 acc[4][4] = {};
  int lr = l >> 2, lc = (l & 3) * 8;
  const short* aA = A + (size_t)(m0 + w * 16 + lr) * K + lc;
  const short* aB = Bt + (size_t)(n0 + w * 16 + lr) * K + lc;
  short* lA0 = As + (w * 64) * 8;        // wave-uniform LDS bases (HW adds lane*16B)
  short* lA1 = As + (256 + w * 64) * 8;
  short* lB0 = Bs + (w * 64) * 8;
  short* lB1 = Bs + (256 + w * 64) * 8;
  int wm = (w & 1) * 64, wn = (w >> 1) * 64;

  for (int kt = 0; kt < K; kt += 32) {
    GLL16(aA, lA0);
    GLL16(aA + (size_t)64 * K, lA1);
    GLL16(aB, lB0);
    GLL16(aB + (size_t)64 * K, lB1);
    aA += 32;
    aB += 32;
    __syncthreads();
    short8 af[4], bfr[4];
#pragma unroll
    for (int mi = 0; mi < 4; mi++)
      af[mi] = *(const short8*)&As[(wm + mi * 16 + (l & 15)) * 32 + (l >> 4) * 8];
#pragma unroll
    for (int ni = 0; ni < 4; ni++)
      bfr[ni] = *(const short8*)&Bs[(wn + ni * 16 + (l & 15)) * 32 + (l >> 4) * 8];
#pragma unroll
    for (int mi = 0; mi < 4; mi++)
#pragma unroll
      for (int ni = 0; ni < 4; ni++)
        acc[mi][ni] = __builtin_amdgcn_mfma_f32_16x16x32_bf16(af[mi], bfr[ni],
                                                              acc[mi][ni], 0, 0, 0);
    __syncthreads();
  }

#pragma unroll
  for (int mi = 0; mi < 4; mi++) {
#pragma unroll
    for (int ni = 0; ni < 4; ni++) {
      int col = n0 + wn + ni * 16 + (l & 15);
      float bcol = bias[col];
#pragma unroll
      for (int r = 0; r < 4; r++) {
        int row = m0 + wm + mi * 16 + (l >> 4) * 4 + r;
        float v = acc[mi][ni][r] + bcol;
        size_t idx = (size_t)row * N + col;
        if (MODE == 0) {
          outb[idx] = f2bf(v);
        } else if (MODE == 1) {
          outf[idx] = v + res[idx];
        } else {
          float ge = 0.5f * v * (1.0f + erff(v * 0.70710678118654752f));
          outb[idx] = f2bf(ge);
        }
      }
    }
  }
}

// ---------------- Flash attention (causal), dk=64, tiles 64q x 64k ----------------
__global__ __launch_bounds__(256) void attn_kernel(const short* __restrict__ q,
                                                   const short* __restrict__ k,
                                                   const short* __restrict__ v,
                                                   short* __restrict__ o) {
  __shared__ short Qs[64 * 64];
  __shared__ short Ks[64 * 64];
  __shared__ short Vt[64 * 64];
  __shared__ short Ps[64 * 64];
  int t = threadIdx.x, w = t >> 6, l = t & 63;
  int qt = blockIdx.x;
  int bh = blockIdx.y;
  int b = bh >> 4, h = bh & 15;
  int q0 = qt * 64;
  size_t base = ((size_t)b * SS) * D_MODEL + (size_t)h * DK;

#pragma unroll
  for (int i = 0; i < 2; i++) {
    int idx = i * 256 + t;
    int row = idx >> 3, ch = idx & 7;
    *(short8*)&Qs[row * 64 + ch * 8] =
        *(const short8*)&q[base + (size_t)(q0 + row) * D_MODEL + ch * 8];
  }
  __syncthreads();
  short8 aq0 = *(const short8*)&Qs[(w * 16 + (l & 15)) * 64 + (l >> 4) * 8];
  short8 aq1 = *(const short8*)&Qs[(w * 16 + (l & 15)) * 64 + 32 + (l >> 4) * 8];

  floatx4 accO[4] = {};
  float mstate[4] = {-1e30f, -1e30f, -1e30f, -1e30f};
  float lstate[4] = {0.f, 0.f, 0.f, 0.f};
  int qrow_base = q0 + w * 16 + (l >> 4) * 4;
  int ntiles = qt + 1;

  for (int kt = 0; kt < ntiles; kt++) {
    int k0 = kt * 64;
    __syncthreads(); // prior iter's reads of Ks/Vt done before restage
#pragma unroll
    for (int i = 0; i < 2; i++) {
      int idx = i * 256 + t;
      int row = idx >> 3, ch = idx & 7;
      *(short8*)&Ks[row * 64 + ch * 8] =
          *(const short8*)&k[base + (size_t)(k0 + row) * D_MODEL + ch * 8];
      short8 vv = *(const short8*)&v[base + (size_t)(k0 + row) * D_MODEL + ch * 8];
#pragma unroll
      for (int j = 0; j < 8; j++)
        Vt[(ch * 8 + j) * 64 + row] = vv[j];
    }
    __syncthreads();

    floatx4 sc[4];
#pragma unroll
    for (int nb = 0; nb < 4; nb++) {
      short8 b0 = *(const short8*)&Ks[(nb * 16 + (l & 15)) * 64 + (l >> 4) * 8];
      short8 b1 = *(const short8*)&Ks[(nb * 16 + (l & 15)) * 64 + 32 + (l >> 4) * 8];
      floatx4 c = {};
      c = __builtin_amdgcn_mfma_f32_16x16x32_bf16(aq0, b0, c, 0, 0, 0);
      c = __builtin_amdgcn_mfma_f32_16x16x32_bf16(aq1, b1, c, 0, 0, 0);
      sc[nb] = c;
    }

#pragma unroll
    for (int r = 0; r < 4; r++) {
      float mx = -1e30f;
#pragma unroll
      for (int nb = 0; nb < 4; nb++) {
        int kcol = k0 + nb * 16 + (l & 15);
        float sv = sc[nb][r] * 0.125f;
        if (kcol > qrow_base + r) sv = -1e30f;
        sc[nb][r] = sv;
        mx = fmaxf(mx, sv);
      }
#pragma unroll
      for (int off = 1; off < 16; off <<= 1) mx = fmaxf(mx, __shfl_xor(mx, off, 64));
      float mnew = fmaxf(mstate[r], mx);
      float alpha = __expf(mstate[r] - mnew);
      float sum = 0.f;
#pragma unroll
      for (int nb = 0; nb < 4; nb++) {
        float p = __expf(sc[nb][r] - mnew);
        sc[nb][r] = p;
        sum += p;
      }
#pragma unroll
      for (int off = 1; off < 16; off <<= 1) sum += __shfl_xor(sum, off, 64);
      lstate[r] = lstate[r] * alpha + sum;
      mstate[r] = mnew;
#pragma unroll
      for (int nb = 0; nb < 4; nb++) accO[nb][r] *= alpha;
    }

    // P: C-layout -> LDS -> A-layout (per-wave private 16 rows, no barrier needed)
#pragma unroll
    for (int nb = 0; nb < 4; nb++)
#pragma unroll
      for (int r = 0; r < 4; r++)
        Ps[(w * 16 + (l >> 4) * 4 + r) * 64 + nb * 16 + (l & 15)] = f2bf(sc[nb][r]);

    short8 pa0 = *(const short8*)&Ps[(w * 16 + (l & 15)) * 64 + (l >> 4) * 8];
    short8 pa1 = *(const short8*)&Ps[(w * 16 + (l & 15)) * 64 + 32 + (l >> 4) * 8];
#pragma unroll
    for (int nb = 0; nb < 4; nb++) {
      short8 b0 = *(const short8*)&Vt[(nb * 16 + (l & 15)) * 64 + (l >> 4) * 8];
      short8 b1 = *(const short8*)&Vt[(nb * 16 + (l & 15)) * 64 + 32 + (l >> 4) * 8];
      accO[nb] = __builtin_amdgcn_mfma_f32_16x16x32_bf16(pa0, b0, accO[nb], 0, 0, 0);
      accO[nb] = __builtin_amdgcn_mfma_f32_16x16x32_bf16(pa1, b1, accO[nb], 0, 0, 0);
    }
  }

#pragma unroll
  for (int nb = 0; nb < 4; nb++)
#pragma unroll
    for (int r = 0; r < 4; r++) {
      float val = accO[nb][r] / lstate[r];
      int row = q0 + w * 16 + (l >> 4) * 4 + r;
      int col = nb * 16 + (l & 15);
      o[base + (size_t)row * D_MODEL + col] = f2bf(val);
    }
}

// ------------------------------ launch ------------------------------
extern "C" void kernel_launch(void* const* d_in, const int* in_sizes, int n_in,
                              void* d_out, int out_size, void* d_ws, size_t ws_size,
                              hipStream_t stream) {
  const float* x = (const float*)d_in[0];
  const float* Wq = (const float*)d_in[1];
  const float* bq = (const float*)d_in[2];
  const float* Wk = (const float*)d_in[3];
  const float* bk = (const float*)d_in[4];
  const float* Wv = (const float*)d_in[5];
  const float* bv = (const float*)d_in[6];
  const float* Wo = (const float*)d_in[7];
  const float* bo = (const float*)d_in[8];
  const float* ln1g = (const float*)d_in[9];
  const float* ln1b = (const float*)d_in[10];
  const float* ln2g = (const float*)d_in[11];
  const float* ln2b = (const float*)d_in[12];
  const float* W1 = (const float*)d_in[13];
  const float* b1 = (const float*)d_in[14];
  const float* W2 = (const float*)d_in[15];
  const float* b2 = (const float*)d_in[16];
  float* out = (float*)d_out;

  char* ws = (char*)d_ws;
  short* wq_t = (short*)ws;                        // 1024x1024 bf16
  short* wk_t = wq_t + 1024 * 1024;
  short* wv_t = wk_t + 1024 * 1024;
  short* wo_t = wv_t + 1024 * 1024;
  short* w1_t = wo_t + 1024 * 1024;                // [4096][1024]
  short* w2_t = w1_t + 1024 * 4096;                // [1024][4096]
  short* h_bf = w2_t + 4096 * 1024;                // [8192][1024] LN out / attn out
  short* qb = h_bf + (size_t)NTOK * D_MODEL;       // [8192][1024]
  short* kb = qb + (size_t)NTOK * D_MODEL;
  short* vb = kb + (size_t)NTOK * D_MODEL;
  short* attnb = vb + (size_t)NTOK * D_MODEL;
  float* x2 = (float*)(attnb + (size_t)NTOK * D_MODEL); // [8192][1024] fp32
  short* ffn1 = qb;                                // reuse q/k/v/attn region (64MB)

  wconvert<<<dim3(16, 16), 256, 0, stream>>>(Wq, wq_t, 1024, 1024);
  wconvert<<<dim3(16, 16), 256, 0, stream>>>(Wk, wk_t, 1024, 1024);
  wconvert<<<dim3(16, 16), 256, 0, stream>>>(Wv, wv_t, 1024, 1024);
  wconvert<<<dim3(16, 16), 256, 0, stream>>>(Wo, wo_t, 1024, 1024);
  wconvert<<<dim3(64, 16), 256, 0, stream>>>(W1, w1_t, 1024, 4096);
  wconvert<<<dim3(16, 64), 256, 0, stream>>>(W2, w2_t, 4096, 1024);

  ln_kernel<<<NTOK, 256, 0, stream>>>(x, ln1g, ln1b, h_bf);

  gemm_bt<0><<<dim3(8, 64), 256, 0, stream>>>(h_bf, wq_t, bq, nullptr, nullptr, qb,
                                              NTOK, 1024, 1024);
  gemm_bt<0><<<dim3(8, 64), 256, 0, stream>>>(h_bf, wk_t, bk, nullptr, nullptr, kb,
                                              NTOK, 1024, 1024);
  gemm_bt<0><<<dim3(8, 64), 256, 0, stream>>>(h_bf, wv_t, bv, nullptr, nullptr, vb,
                                              NTOK, 1024, 1024);

  attn_kernel<<<dim3(32, 64), 256, 0, stream>>>(qb, kb, vb, attnb);

  gemm_bt<1><<<dim3(8, 64), 256, 0, stream>>>(attnb, wo_t, bo, x, x2, nullptr,
                                              NTOK, 1024, 1024);

  ln_kernel<<<NTOK, 256, 0, stream>>>(x2, ln2g, ln2b, h_bf);

  gemm_bt<2><<<dim3(32, 64), 256, 0, stream>>>(h_bf, w1_t, b1, nullptr, nullptr,
                                               ffn1, NTOK, 4096, 1024);

  gemm_bt<1><<<dim3(8, 64), 256, 0, stream>>>(ffn1, w2_t, b2, x2, out, nullptr,
                                              NTOK, 1024, 4096);
}

// Round 3
// 648.922 us; speedup vs baseline: 1.3821x; 1.3821x over previous
//
#include <hip/hip_runtime.h>
#include <hip/hip_bf16.h>
#include <math.h>

typedef __attribute__((ext_vector_type(8))) short short8;
typedef __attribute__((ext_vector_type(4))) float floatx4;
typedef __attribute__((ext_vector_type(4))) short short4v;

#define D_MODEL 1024
#define N_HEADS 16
#define DK 64
#define D_FF 4096
#define BB 4
#define SS 2048
#define NTOK (BB * SS) /* 8192 */
#define LN_EPS 1e-5f

static __device__ __forceinline__ short f2bf(float f) {
  union { float f; unsigned int u; } v;
  v.f = f;
  unsigned int u = v.u;
  unsigned int r = u + 0x7fffu + ((u >> 16) & 1u); // round-to-nearest-even
  return (short)(r >> 16);
}

#define GLL16(g, l)                                                            \
  __builtin_amdgcn_global_load_lds(                                            \
      (const __attribute__((address_space(1))) void*)(g),                      \
      (__attribute__((address_space(3))) void*)(l), 16, 0, 0)

// ---------------- LayerNorm: fp32 row -> bf16 row ----------------
__global__ __launch_bounds__(256) void ln_kernel(const float* __restrict__ x,
                                                 const float* __restrict__ g,
                                                 const float* __restrict__ b,
                                                 short* __restrict__ out) {
  int row = blockIdx.x;
  int t = threadIdx.x;
  const float4* rp = (const float4*)(x + (size_t)row * D_MODEL);
  float4 v = rp[t];
  float s = v.x + v.y + v.z + v.w;
  float ss = v.x * v.x + v.y * v.y + v.z * v.z + v.w * v.w;
#pragma unroll
  for (int off = 32; off >= 1; off >>= 1) {
    s += __shfl_xor(s, off, 64);
    ss += __shfl_xor(ss, off, 64);
  }
  __shared__ float red[8];
  int wv = t >> 6;
  if ((t & 63) == 0) { red[wv] = s; red[wv + 4] = ss; }
  __syncthreads();
  s = red[0] + red[1] + red[2] + red[3];
  ss = red[4] + red[5] + red[6] + red[7];
  float mu = s * (1.0f / D_MODEL);
  float var = ss * (1.0f / D_MODEL) - mu * mu;
  float rstd = rsqrtf(var + LN_EPS);
  float4 gv = ((const float4*)g)[t];
  float4 bv = ((const float4*)b)[t];
  short4v o;
  o.x = f2bf((v.x - mu) * rstd * gv.x + bv.x);
  o.y = f2bf((v.y - mu) * rstd * gv.y + bv.y);
  o.z = f2bf((v.z - mu) * rstd * gv.z + bv.z);
  o.w = f2bf((v.w - mu) * rstd * gv.w + bv.w);
  *(short4v*)(out + (size_t)row * D_MODEL + t * 4) = o;
}

// ------------- Weight convert+transpose: W[K][N] f32 -> Wt[N][K] bf16 -------------
__global__ __launch_bounds__(256) void wconvert(const float* __restrict__ W,
                                                short* __restrict__ Wt, int K, int N) {
  __shared__ float tile[64][65];
  int n0 = blockIdx.x * 64, k0 = blockIdx.y * 64;
  int t = threadIdx.x;
  int c = t & 63, r0 = t >> 6;
#pragma unroll
  for (int i = 0; i < 16; i++) {
    int r = r0 + i * 4;
    tile[r][c] = W[(size_t)(k0 + r) * N + n0 + c];
  }
  __syncthreads();
#pragma unroll
  for (int i = 0; i < 16; i++) {
    int r = r0 + i * 4;
    Wt[(size_t)(n0 + r) * K + k0 + c] = f2bf(tile[c][r]);
  }
}

// ---------------- GEMM: C[M,N] = A[M,K](bf16) x Bt[N,K](bf16) + bias -------------
// MODE 0: +bias -> bf16 out
// MODE 1: +bias +res(fp32) -> fp32 out
// MODE 2: +bias, exact GELU -> bf16 out
template <int MODE>
__global__ __launch_bounds__(256) void gemm_bt(const short* __restrict__ A,
                                               const short* __restrict__ Bt,
                                               const float* __restrict__ bias,
                                               const float* __restrict__ res,
                                               float* __restrict__ outf,
                                               short* __restrict__ outb,
                                               int M, int N, int K) {
  __shared__ short As[128 * 32];
  __shared__ short Bs[128 * 32];
  int t = threadIdx.x;
  int w = t >> 6, l = t & 63;
  int m0 = blockIdx.y * 128, n0 = blockIdx.x * 128;
  floatx4 acc[4][4] = {};
  int lr = l >> 2, lc = (l & 3) * 8;
  const short* aA = A + (size_t)(m0 + w * 16 + lr) * K + lc;
  const short* aB = Bt + (size_t)(n0 + w * 16 + lr) * K + lc;
  short* lA0 = As + (w * 64) * 8;        // wave-uniform LDS bases (HW adds lane*16B)
  short* lA1 = As + (256 + w * 64) * 8;
  short* lB0 = Bs + (w * 64) * 8;
  short* lB1 = Bs + (256 + w * 64) * 8;
  int wm = (w & 1) * 64, wn = (w >> 1) * 64;

  for (int kt = 0; kt < K; kt += 32) {
    GLL16(aA, lA0);
    GLL16(aA + (size_t)64 * K, lA1);
    GLL16(aB, lB0);
    GLL16(aB + (size_t)64 * K, lB1);
    aA += 32;
    aB += 32;
    __syncthreads();
    short8 af[4], bfr[4];
#pragma unroll
    for (int mi = 0; mi < 4; mi++)
      af[mi] = *(const short8*)&As[(wm + mi * 16 + (l & 15)) * 32 + (l >> 4) * 8];
#pragma unroll
    for (int ni = 0; ni < 4; ni++)
      bfr[ni] = *(const short8*)&Bs[(wn + ni * 16 + (l & 15)) * 32 + (l >> 4) * 8];
#pragma unroll
    for (int mi = 0; mi < 4; mi++)
#pragma unroll
      for (int ni = 0; ni < 4; ni++)
        acc[mi][ni] = __builtin_amdgcn_mfma_f32_16x16x32_bf16(af[mi], bfr[ni],
                                                              acc[mi][ni], 0, 0, 0);
    __syncthreads();
  }

#pragma unroll
  for (int mi = 0; mi < 4; mi++) {
#pragma unroll
    for (int ni = 0; ni < 4; ni++) {
      int col = n0 + wn + ni * 16 + (l & 15);
      float bcol = bias[col];
#pragma unroll
      for (int r = 0; r < 4; r++) {
        int row = m0 + wm + mi * 16 + (l >> 4) * 4 + r;
        float v = acc[mi][ni][r] + bcol;
        size_t idx = (size_t)row * N + col;
        if (MODE == 0) {
          outb[idx] = f2bf(v);
        } else if (MODE == 1) {
          outf[idx] = v + res[idx];
        } else {
          float ge = 0.5f * v * (1.0f + erff(v * 0.70710678118654752f));
          outb[idx] = f2bf(ge);
        }
      }
    }
  }
}

// ------------- V transpose prepass: qkv v-cols -> vt[bh][d][s] -------------
__global__ __launch_bounds__(256) void vtrans(const short* __restrict__ qkv,
                                              short* __restrict__ vt) {
  __shared__ short Ls[64][72];
  int t = threadIdx.x;
  int s0 = blockIdx.x * 64;
  int bh = blockIdx.y;
  int b = bh >> 4, h = bh & 15;
  const short* vsrc = qkv + (size_t)b * SS * 3072 + 2048 + h * 64;
#pragma unroll
  for (int it = 0; it < 2; it++) {
    int idx = it * 256 + t;
    int sr = idx >> 3, ch = idx & 7;
    *(short8*)&Ls[sr][ch * 8] =
        *(const short8*)&vsrc[(size_t)(s0 + sr) * 3072 + ch * 8];
  }
  __syncthreads();
  int d = t >> 2, sb = (t & 3) * 16;
  short tmp[16];
#pragma unroll
  for (int j = 0; j < 16; j++) tmp[j] = Ls[sb + j][d];
  short8* dst = (short8*)&vt[(size_t)bh * DK * SS + (size_t)d * SS + s0 + sb];
  dst[0] = *(short8*)&tmp[0];
  dst[1] = *(short8*)&tmp[8];
}

// ------- Flash attention (causal): 128-q-row tiles, paired scheduling -------
// qkv: [8192][3072] bf16 (q|k|v), vt: [64 bh][64 d][2048 s], o: [8192][1024]
__global__ __launch_bounds__(256) void attn_kernel(const short* __restrict__ qkv,
                                                   const short* __restrict__ vt,
                                                   short* __restrict__ o) {
  __shared__ short Qs[128 * 64];   // 16 KB
  __shared__ short Ks[64 * 64];    // 8 KB
  __shared__ short Vs[64 * 64];    // 8 KB (rows = d, cols = k within tile)
  __shared__ short Ps[128 * 72];   // 18 KB, padded stride 72 (conflict-free writes)
  int t = threadIdx.x, w = t >> 6, l = t & 63;
  int p = blockIdx.x;   // 0..7 -> q-tiles {p, 15-p}: uniform 34 iters/block
  int bh = blockIdx.y;
  int b = bh >> 4, h = bh & 15;
  const short* qbase = qkv + (size_t)b * SS * 3072 + h * DK;
  const short* kbase = qbase + 1024;
  const short* vbase = vt + (size_t)bh * DK * SS;
  short* obase = o + (size_t)b * SS * D_MODEL + h * DK;  // batch offset! (R2 bug)
  int l7 = l & 7, l3 = l >> 3;   // staging lane split
  int lm = l & 15, lq = l >> 4;  // fragment lane split

  for (int ph = 0; ph < 2; ph++) {
    int qi = ph ? (15 - p) : p;
    int q0 = qi * 128;
    // ---- stage Q (wave w owns rows [w*32, w*32+32)) ----
#pragma unroll
    for (int j = 0; j < 4; j++) {
      int r8 = w * 32 + j * 8;
      GLL16(qbase + (size_t)(q0 + r8 + l3) * 3072 + l7 * 8, Qs + r8 * 64);
    }
    __syncthreads();  // drains vmcnt -> Qs valid
    short8 aq[2][2];
#pragma unroll
    for (int m = 0; m < 2; m++)
#pragma unroll
      for (int hf = 0; hf < 2; hf++)
        aq[m][hf] =
            *(const short8*)&Qs[(w * 32 + m * 16 + lm) * 64 + hf * 32 + lq * 8];

    floatx4 accO[2][4] = {};
    float mst[2][4], lst[2][4];
#pragma unroll
    for (int m = 0; m < 2; m++)
#pragma unroll
      for (int r = 0; r < 4; r++) { mst[m][r] = -1e30f; lst[m][r] = 0.f; }

    int wrow_max = q0 + w * 32 + 31;
    int ntile = 2 * qi + 2;
    for (int kt = 0; kt < ntile; kt++) {
      int k0 = kt * 64;
      __syncthreads();  // all reads of Ks/Vs from prev iter done
#pragma unroll
      for (int j = 0; j < 2; j++) {
        int r8 = (w * 2 + j) * 8;
        GLL16(kbase + (size_t)(k0 + r8 + l3) * 3072 + l7 * 8, Ks + r8 * 64);
        GLL16(vbase + (size_t)(r8 + l3) * SS + k0 + l7 * 8, Vs + r8 * 64);
      }
      __syncthreads();  // staging visible

      if (k0 <= wrow_max) {  // wave-uniform: skip fully-masked tiles
        // ---- QK^T ----
        floatx4 sc[2][4];
#pragma unroll
        for (int nb = 0; nb < 4; nb++) {
          short8 k0f = *(const short8*)&Ks[(nb * 16 + lm) * 64 + lq * 8];
          short8 k1f = *(const short8*)&Ks[(nb * 16 + lm) * 64 + 32 + lq * 8];
#pragma unroll
          for (int m = 0; m < 2; m++) {
            floatx4 z = {};
            z = __builtin_amdgcn_mfma_f32_16x16x32_bf16(aq[m][0], k0f, z, 0, 0, 0);
            z = __builtin_amdgcn_mfma_f32_16x16x32_bf16(aq[m][1], k1f, z, 0, 0, 0);
            sc[m][nb] = z;
          }
        }
        // ---- online softmax (rows: lq*4+r; cols: nb*16+lm) ----
#pragma unroll
        for (int m = 0; m < 2; m++) {
#pragma unroll
          for (int r = 0; r < 4; r++) {
            int rowg = q0 + w * 32 + m * 16 + lq * 4 + r;
            float mx = -1e30f;
#pragma unroll
            for (int nb = 0; nb < 4; nb++) {
              int colg = k0 + nb * 16 + lm;
              float sv = sc[m][nb][r] * 0.125f;
              sv = (colg > rowg) ? -1e30f : sv;
              sc[m][nb][r] = sv;
              mx = fmaxf(mx, sv);
            }
#pragma unroll
            for (int off = 1; off < 16; off <<= 1)
              mx = fmaxf(mx, __shfl_xor(mx, off, 64));
            float mnew = fmaxf(mst[m][r], mx);
            float alpha = __expf(mst[m][r] - mnew);
            float sum = 0.f;
#pragma unroll
            for (int nb = 0; nb < 4; nb++) {
              float pv = __expf(sc[m][nb][r] - mnew);
              sc[m][nb][r] = pv;
              sum += pv;
            }
#pragma unroll
            for (int off = 1; off < 16; off <<= 1) sum += __shfl_xor(sum, off, 64);
            lst[m][r] = lst[m][r] * alpha + sum;
            mst[m][r] = mnew;
#pragma unroll
            for (int nb = 0; nb < 4; nb++) accO[m][nb][r] *= alpha;
          }
        }
        // ---- P: C-layout -> LDS (padded, wave-private) -> A-layout ----
#pragma unroll
        for (int m = 0; m < 2; m++)
#pragma unroll
          for (int nb = 0; nb < 4; nb++)
#pragma unroll
            for (int r = 0; r < 4; r++)
              Ps[(w * 32 + m * 16 + lq * 4 + r) * 72 + nb * 16 + lm] =
                  f2bf(sc[m][nb][r]);
        short8 pa[2][2];
#pragma unroll
        for (int m = 0; m < 2; m++)
#pragma unroll
          for (int hf = 0; hf < 2; hf++)
            pa[m][hf] =
                *(const short8*)&Ps[(w * 32 + m * 16 + lm) * 72 + hf * 32 + lq * 8];
        // ---- P @ V ----
#pragma unroll
        for (int nb = 0; nb < 4; nb++) {
          short8 v0f = *(const short8*)&Vs[(nb * 16 + lm) * 64 + lq * 8];
          short8 v1f = *(const short8*)&Vs[(nb * 16 + lm) * 64 + 32 + lq * 8];
#pragma unroll
          for (int m = 0; m < 2; m++) {
            accO[m][nb] = __builtin_amdgcn_mfma_f32_16x16x32_bf16(pa[m][0], v0f,
                                                                  accO[m][nb], 0, 0, 0);
            accO[m][nb] = __builtin_amdgcn_mfma_f32_16x16x32_bf16(pa[m][1], v1f,
                                                                  accO[m][nb], 0, 0, 0);
          }
        }
      }
    }
    // ---- output ----
#pragma unroll
    for (int m = 0; m < 2; m++)
#pragma unroll
      for (int nb = 0; nb < 4; nb++)
#pragma unroll
        for (int r = 0; r < 4; r++) {
          float val = accO[m][nb][r] / lst[m][r];
          int rowg = q0 + w * 32 + m * 16 + lq * 4 + r;
          obase[(size_t)rowg * D_MODEL + nb * 16 + lm] = f2bf(val);
        }
  }
}

// ------------------------------ launch ------------------------------
extern "C" void kernel_launch(void* const* d_in, const int* in_sizes, int n_in,
                              void* d_out, int out_size, void* d_ws, size_t ws_size,
                              hipStream_t stream) {
  const float* x = (const float*)d_in[0];
  const float* Wq = (const float*)d_in[1];
  const float* bq = (const float*)d_in[2];
  const float* Wk = (const float*)d_in[3];
  const float* bk = (const float*)d_in[4];
  const float* Wv = (const float*)d_in[5];
  const float* bv = (const float*)d_in[6];
  const float* Wo = (const float*)d_in[7];
  const float* bo = (const float*)d_in[8];
  const float* ln1g = (const float*)d_in[9];
  const float* ln1b = (const float*)d_in[10];
  const float* ln2g = (const float*)d_in[11];
  const float* ln2b = (const float*)d_in[12];
  const float* W1 = (const float*)d_in[13];
  const float* b1 = (const float*)d_in[14];
  const float* W2 = (const float*)d_in[15];
  const float* b2 = (const float*)d_in[16];
  float* out = (float*)d_out;

  // ---- workspace layout (~104 MB) ----
  short* wqkv_t = (short*)d_ws;                     // [3072][1024] (Wq|Wk|Wv rows)
  short* wo_t = wqkv_t + 3072 * 1024;               // [1024][1024]
  short* w1_t = wo_t + 1024 * 1024;                 // [4096][1024]
  short* w2_t = w1_t + 4096 * 1024;                 // [1024][4096]
  float* bqkv = (float*)(w2_t + 1024 * 4096);       // [3072]
  short* h_bf = (short*)(bqkv + 3072);              // [8192][1024] LN out / attn out
  short* qkvb = h_bf + (size_t)NTOK * D_MODEL;      // [8192][3072]
  short* vtg = qkvb + (size_t)NTOK * 3072;          // [64][64][2048]
  short* ffn1 = qkvb;  // overlay: qkvb+vtg = exactly 8192*4096 shorts

  wconvert<<<dim3(16, 16), 256, 0, stream>>>(Wq, wqkv_t, 1024, 1024);
  wconvert<<<dim3(16, 16), 256, 0, stream>>>(Wk, wqkv_t + 1024 * 1024, 1024, 1024);
  wconvert<<<dim3(16, 16), 256, 0, stream>>>(Wv, wqkv_t + 2048 * 1024, 1024, 1024);
  wconvert<<<dim3(16, 16), 256, 0, stream>>>(Wo, wo_t, 1024, 1024);
  wconvert<<<dim3(64, 16), 256, 0, stream>>>(W1, w1_t, 1024, 4096);
  wconvert<<<dim3(16, 64), 256, 0, stream>>>(W2, w2_t, 4096, 1024);
  hipMemcpyAsync(bqkv, bq, 1024 * sizeof(float), hipMemcpyDeviceToDevice, stream);
  hipMemcpyAsync(bqkv + 1024, bk, 1024 * sizeof(float), hipMemcpyDeviceToDevice, stream);
  hipMemcpyAsync(bqkv + 2048, bv, 1024 * sizeof(float), hipMemcpyDeviceToDevice, stream);

  ln_kernel<<<NTOK, 256, 0, stream>>>(x, ln1g, ln1b, h_bf);

  // fused QKV GEMM: [8192][1024] x [3072][1024]^T -> [8192][3072]
  gemm_bt<0><<<dim3(24, 64), 256, 0, stream>>>(h_bf, wqkv_t, bqkv, nullptr, nullptr,
                                               qkvb, NTOK, 3072, 1024);

  vtrans<<<dim3(SS / 64, 64), 256, 0, stream>>>(qkvb, vtg);

  attn_kernel<<<dim3(8, 64), 256, 0, stream>>>(qkvb, vtg, h_bf);

  // O-proj + residual -> d_out (fp32 residual stream lives in d_out)
  gemm_bt<1><<<dim3(8, 64), 256, 0, stream>>>(h_bf, wo_t, bo, x, out, nullptr,
                                              NTOK, 1024, 1024);

  ln_kernel<<<NTOK, 256, 0, stream>>>(out, ln2g, ln2b, h_bf);

  gemm_bt<2><<<dim3(32, 64), 256, 0, stream>>>(h_bf, w1_t, b1, nullptr, nullptr,
                                               ffn1, NTOK, 4096, 1024);

  gemm_bt<1><<<dim3(8, 64), 256, 0, stream>>>(ffn1, w2_t, b2, out, out, nullptr,
                                              NTOK, 1024, 4096);
}

// Round 4
// 582.323 us; speedup vs baseline: 1.5402x; 1.1144x over previous
//
#include <hip/hip_runtime.h>
#include <hip/hip_bf16.h>
#include <math.h>

typedef __attribute__((ext_vector_type(8))) short short8;
typedef __attribute__((ext_vector_type(4))) float floatx4;
typedef __attribute__((ext_vector_type(4))) short short4v;

#define D_MODEL 1024
#define N_HEADS 16
#define DK 64
#define D_FF 4096
#define BB 4
#define SS 2048
#define NTOK (BB * SS) /* 8192 */
#define LN_EPS 1e-5f
#define SCL 0.18033688011112042f /* 0.125 * log2(e) */

static __device__ __forceinline__ short f2bf(float f) {
  union { float f; unsigned int u; } v;
  v.f = f;
  unsigned int u = v.u;
  unsigned int r = u + 0x7fffu + ((u >> 16) & 1u); // round-to-nearest-even
  return (short)(r >> 16);
}

#define GLL16(g, l)                                                            \
  __builtin_amdgcn_global_load_lds(                                            \
      (const __attribute__((address_space(1))) void*)(g),                      \
      (__attribute__((address_space(3))) void*)(l), 16, 0, 0)

// ---------------- LayerNorm: fp32 row -> bf16 row ----------------
__global__ __launch_bounds__(256) void ln_kernel(const float* __restrict__ x,
                                                 const float* __restrict__ g,
                                                 const float* __restrict__ b,
                                                 short* __restrict__ out) {
  int row = blockIdx.x;
  int t = threadIdx.x;
  const float4* rp = (const float4*)(x + (size_t)row * D_MODEL);
  float4 v = rp[t];
  float s = v.x + v.y + v.z + v.w;
  float ss = v.x * v.x + v.y * v.y + v.z * v.z + v.w * v.w;
#pragma unroll
  for (int off = 32; off >= 1; off >>= 1) {
    s += __shfl_xor(s, off, 64);
    ss += __shfl_xor(ss, off, 64);
  }
  __shared__ float red[8];
  int wv = t >> 6;
  if ((t & 63) == 0) { red[wv] = s; red[wv + 4] = ss; }
  __syncthreads();
  s = red[0] + red[1] + red[2] + red[3];
  ss = red[4] + red[5] + red[6] + red[7];
  float mu = s * (1.0f / D_MODEL);
  float var = ss * (1.0f / D_MODEL) - mu * mu;
  float rstd = rsqrtf(var + LN_EPS);
  float4 gv = ((const float4*)g)[t];
  float4 bv = ((const float4*)b)[t];
  short4v o;
  o.x = f2bf((v.x - mu) * rstd * gv.x + bv.x);
  o.y = f2bf((v.y - mu) * rstd * gv.y + bv.y);
  o.z = f2bf((v.z - mu) * rstd * gv.z + bv.z);
  o.w = f2bf((v.w - mu) * rstd * gv.w + bv.w);
  *(short4v*)(out + (size_t)row * D_MODEL + t * 4) = o;
}

// ---- Merged weight convert+transpose: all 6 weights in one launch ----
// blocks 0..1023: Wq/Wk/Wv/Wo (1024x1024); 1024..2047: W1; 2048..3071: W2
__global__ __launch_bounds__(256) void wconvert_all(
    const float* __restrict__ Wq, const float* __restrict__ Wk,
    const float* __restrict__ Wv, const float* __restrict__ Wo,
    const float* __restrict__ W1, const float* __restrict__ W2,
    short* __restrict__ wqkv_t, short* __restrict__ wo_t,
    short* __restrict__ w1_t, short* __restrict__ w2_t) {
  __shared__ float tile[64][65];
  int id = blockIdx.x;
  const float* W;
  short* Wt;
  int K, N, tid;
  if (id < 1024) {
    int wsel = id >> 8;
    tid = id & 255;
    K = 1024; N = 1024;
    W = wsel == 0 ? Wq : wsel == 1 ? Wk : wsel == 2 ? Wv : Wo;
    Wt = wsel < 3 ? wqkv_t + (size_t)wsel * 1024 * 1024 : wo_t;
  } else if (id < 2048) {
    tid = id - 1024; K = 1024; N = 4096; W = W1; Wt = w1_t;
  } else {
    tid = id - 2048; K = 4096; N = 1024; W = W2; Wt = w2_t;
  }
  int ntn = N >> 6;
  int n0 = (tid % ntn) * 64, k0 = (tid / ntn) * 64;
  int t = threadIdx.x;
  int c = t & 63, r0 = t >> 6;
#pragma unroll
  for (int i = 0; i < 16; i++) {
    int r = r0 + i * 4;
    tile[r][c] = W[(size_t)(k0 + r) * N + n0 + c];
  }
  __syncthreads();
#pragma unroll
  for (int i = 0; i < 16; i++) {
    int r = r0 + i * 4;
    Wt[(size_t)(n0 + r) * K + k0 + c] = f2bf(tile[c][r]);
  }
}

// ---------------- GEMM: C[M,N] = A[M,K](bf16) x Bt[N,K](bf16) + bias -------------
// XOR-swizzled LDS chunks: staging lane loads chunk (l&3)^(lr&3); reader
// indexes chunk (lq ^ (lm&3)) -> conflict-free ds_read_b128.
// MODE 0: +bias -> bf16 out; MODE 1: +bias +res(fp32) -> fp32 out;
// MODE 2: +bias, exact GELU -> bf16 out
template <int MODE>
__global__ __launch_bounds__(256) void gemm_bt(const short* __restrict__ A,
                                               const short* __restrict__ Bt,
                                               const float* __restrict__ bias,
                                               const float* __restrict__ res,
                                               float* __restrict__ outf,
                                               short* __restrict__ outb,
                                               int M, int N, int K) {
  __shared__ short As[128 * 32];
  __shared__ short Bs[128 * 32];
  int t = threadIdx.x;
  int w = t >> 6, l = t & 63;
  int lm = l & 15, lq = l >> 4;
  int m0 = blockIdx.y * 128, n0 = blockIdx.x * 128;
  floatx4 acc[4][4] = {};
  int lr = l >> 2;
  int lc = ((l & 3) ^ (lr & 3)) * 8;  // swizzled source chunk
  const short* aA = A + (size_t)(m0 + w * 16 + lr) * K + lc;
  const short* aB = Bt + (size_t)(n0 + w * 16 + lr) * K + lc;
  short* lA0 = As + (w * 64) * 8;
  short* lA1 = As + (256 + w * 64) * 8;
  short* lB0 = Bs + (w * 64) * 8;
  short* lB1 = Bs + (256 + w * 64) * 8;
  int wm = (w & 1) * 64, wn = (w >> 1) * 64;
  int sw3 = lm & 3;
  int rdoff = ((lq ^ sw3) * 8);

  for (int kt = 0; kt < K; kt += 32) {
    GLL16(aA, lA0);
    GLL16(aA + (size_t)64 * K, lA1);
    GLL16(aB, lB0);
    GLL16(aB + (size_t)64 * K, lB1);
    aA += 32;
    aB += 32;
    __syncthreads();
    short8 af[4], bfr[4];
#pragma unroll
    for (int mi = 0; mi < 4; mi++)
      af[mi] = *(const short8*)&As[(wm + mi * 16 + lm) * 32 + rdoff];
#pragma unroll
    for (int ni = 0; ni < 4; ni++)
      bfr[ni] = *(const short8*)&Bs[(wn + ni * 16 + lm) * 32 + rdoff];
#pragma unroll
    for (int mi = 0; mi < 4; mi++)
#pragma unroll
      for (int ni = 0; ni < 4; ni++)
        acc[mi][ni] = __builtin_amdgcn_mfma_f32_16x16x32_bf16(af[mi], bfr[ni],
                                                              acc[mi][ni], 0, 0, 0);
    __syncthreads();
  }

#pragma unroll
  for (int mi = 0; mi < 4; mi++) {
#pragma unroll
    for (int ni = 0; ni < 4; ni++) {
      int col = n0 + wn + ni * 16 + lm;
      float bcol = bias[col];
#pragma unroll
      for (int r = 0; r < 4; r++) {
        int row = m0 + wm + mi * 16 + lq * 4 + r;
        float v = acc[mi][ni][r] + bcol;
        size_t idx = (size_t)row * N + col;
        if (MODE == 0) {
          outb[idx] = f2bf(v);
        } else if (MODE == 1) {
          outf[idx] = v + res[idx];
        } else {
          float ge = 0.5f * v * (1.0f + erff(v * 0.70710678118654752f));
          outb[idx] = f2bf(ge);
        }
      }
    }
  }
}

// ------------- V transpose prepass: qkv v-cols -> vt[bh][d][s] -------------
__global__ __launch_bounds__(256) void vtrans(const short* __restrict__ qkv,
                                              short* __restrict__ vt) {
  __shared__ short Ls[64][72];
  int t = threadIdx.x;
  int s0 = blockIdx.x * 64;
  int bh = blockIdx.y;
  int b = bh >> 4, h = bh & 15;
  const short* vsrc = qkv + (size_t)b * SS * 3072 + 2048 + h * 64;
#pragma unroll
  for (int it = 0; it < 2; it++) {
    int idx = it * 256 + t;
    int sr = idx >> 3, ch = idx & 7;
    *(short8*)&Ls[sr][ch * 8] =
        *(const short8*)&vsrc[(size_t)(s0 + sr) * 3072 + ch * 8];
  }
  __syncthreads();
  int d = t >> 2, sb = (t & 3) * 16;
  short tmp[16];
#pragma unroll
  for (int j = 0; j < 16; j++) tmp[j] = Ls[sb + j][d];
  short8* dst = (short8*)&vt[(size_t)bh * DK * SS + (size_t)d * SS + s0 + sb];
  dst[0] = *(short8*)&tmp[0];
  dst[1] = *(short8*)&tmp[8];
}

// ------- Flash attention (causal): no-max softmax, swizzled LDS -------
// grid (bh=64, p=8): p-blocks of one bh share an XCD (L2 K/V reuse).
__global__ __launch_bounds__(256) void attn_kernel(const short* __restrict__ qkv,
                                                   const short* __restrict__ vt,
                                                   short* __restrict__ o) {
  __shared__ short Qs[128 * 64];   // 16 KB, swizzled chunks
  __shared__ short Ks[64 * 64];    // 8 KB, swizzled
  __shared__ short Vs[64 * 64];    // 8 KB, swizzled (rows=d, cols=k)
  __shared__ short Ps[128 * 72];   // 18 KB, padded stride 72
  int t = threadIdx.x, w = t >> 6, l = t & 63;
  int bh = blockIdx.x;
  int p = blockIdx.y;   // 0..7 -> q-tiles {p, 15-p}
  int b = bh >> 4, h = bh & 15;
  const short* qbase = qkv + (size_t)b * SS * 3072 + h * DK;
  const short* kbase = qbase + 1024;
  const short* vbase = vt + (size_t)bh * DK * SS;
  short* obase = o + (size_t)b * SS * D_MODEL + h * DK;
  int l7 = l & 7, l3 = l >> 3;
  int c7 = (l7 ^ l3) * 8;        // swizzled staging chunk offset (shorts)
  int lm = l & 15, lq = l >> 4;
  int swq = lm & 7;              // reader swizzle key

  for (int ph = 0; ph < 2; ph++) {
    int qi = ph ? (15 - p) : p;
    int q0 = qi * 128;
#pragma unroll
    for (int j = 0; j < 4; j++) {
      int r8 = w * 32 + j * 8;
      GLL16(qbase + (size_t)(q0 + r8 + l3) * 3072 + c7, Qs + r8 * 64);
    }
    __syncthreads();
    short8 aq[2][2];
#pragma unroll
    for (int m = 0; m < 2; m++)
#pragma unroll
      for (int hf = 0; hf < 2; hf++)
        aq[m][hf] = *(const short8*)&Qs[(w * 32 + m * 16 + lm) * 64 +
                                        ((hf * 4 + lq) ^ swq) * 8];

    floatx4 accO[2][4] = {};
    float lst[2][4] = {};
    int wrow_min = q0 + w * 32;
    int wrow_max = wrow_min + 31;
    int ntile = 2 * qi + 2;
    for (int kt = 0; kt < ntile; kt++) {
      int k0 = kt * 64;
      __syncthreads();  // prev-iter Ks/Vs reads done
#pragma unroll
      for (int j = 0; j < 2; j++) {
        int r8 = (w * 2 + j) * 8;
        GLL16(kbase + (size_t)(k0 + r8 + l3) * 3072 + c7, Ks + r8 * 64);
        GLL16(vbase + (size_t)(r8 + l3) * SS + k0 + c7, Vs + r8 * 64);
      }
      __syncthreads();  // staging visible

      if (k0 <= wrow_max) {  // wave-uniform tile skip
        // ---- QK^T ----
        floatx4 sc[2][4];
#pragma unroll
        for (int nb = 0; nb < 4; nb++) {
          short8 k0f = *(const short8*)&Ks[(nb * 16 + lm) * 64 + (lq ^ swq) * 8];
          short8 k1f =
              *(const short8*)&Ks[(nb * 16 + lm) * 64 + ((4 + lq) ^ swq) * 8];
#pragma unroll
          for (int m = 0; m < 2; m++) {
            floatx4 z = {};
            z = __builtin_amdgcn_mfma_f32_16x16x32_bf16(aq[m][0], k0f, z, 0, 0, 0);
            z = __builtin_amdgcn_mfma_f32_16x16x32_bf16(aq[m][1], k1f, z, 0, 0, 0);
            sc[m][nb] = z;
          }
        }
        // ---- no-max softmax: p = exp2(s*0.125*log2e); lane-partial sums ----
        if (k0 + 63 <= wrow_min) {  // fully unmasked (wave-uniform)
#pragma unroll
          for (int m = 0; m < 2; m++)
#pragma unroll
            for (int r = 0; r < 4; r++)
#pragma unroll
              for (int nb = 0; nb < 4; nb++) {
                float pv = exp2f(sc[m][nb][r] * SCL);
                sc[m][nb][r] = pv;
                lst[m][r] += pv;
              }
        } else {
#pragma unroll
          for (int m = 0; m < 2; m++)
#pragma unroll
            for (int r = 0; r < 4; r++) {
              int rowg = q0 + w * 32 + m * 16 + lq * 4 + r;
#pragma unroll
              for (int nb = 0; nb < 4; nb++) {
                int colg = k0 + nb * 16 + lm;
                float pv = (colg > rowg) ? 0.f : exp2f(sc[m][nb][r] * SCL);
                sc[m][nb][r] = pv;
                lst[m][r] += pv;
              }
            }
        }
        // ---- P: C-layout -> LDS (truncated bf16) -> A-layout ----
#pragma unroll
        for (int m = 0; m < 2; m++)
#pragma unroll
          for (int nb = 0; nb < 4; nb++)
#pragma unroll
            for (int r = 0; r < 4; r++) {
              union { float f; unsigned int u; } cv;
              cv.f = sc[m][nb][r];
              Ps[(w * 32 + m * 16 + lq * 4 + r) * 72 + nb * 16 + lm] =
                  (short)(cv.u >> 16);
            }
        short8 pa[2][2];
#pragma unroll
        for (int m = 0; m < 2; m++)
#pragma unroll
          for (int hf = 0; hf < 2; hf++)
            pa[m][hf] =
                *(const short8*)&Ps[(w * 32 + m * 16 + lm) * 72 + hf * 32 + lq * 8];
        // ---- P @ V ----
#pragma unroll
        for (int nb = 0; nb < 4; nb++) {
          short8 v0f = *(const short8*)&Vs[(nb * 16 + lm) * 64 + (lq ^ swq) * 8];
          short8 v1f =
              *(const short8*)&Vs[(nb * 16 + lm) * 64 + ((4 + lq) ^ swq) * 8];
#pragma unroll
          for (int m = 0; m < 2; m++) {
            accO[m][nb] = __builtin_amdgcn_mfma_f32_16x16x32_bf16(pa[m][0], v0f,
                                                                  accO[m][nb], 0, 0, 0);
            accO[m][nb] = __builtin_amdgcn_mfma_f32_16x16x32_bf16(pa[m][1], v1f,
                                                                  accO[m][nb], 0, 0, 0);
          }
        }
      }
    }
    // ---- epilogue: cross-lane row-sum reduce (lm bits), then normalize ----
#pragma unroll
    for (int m = 0; m < 2; m++)
#pragma unroll
      for (int r = 0; r < 4; r++) {
        float s = lst[m][r];
        s += __shfl_xor(s, 1, 64);
        s += __shfl_xor(s, 2, 64);
        s += __shfl_xor(s, 4, 64);
        s += __shfl_xor(s, 8, 64);
        float inv = 1.0f / s;
        int rowg = q0 + w * 32 + m * 16 + lq * 4 + r;
#pragma unroll
        for (int nb = 0; nb < 4; nb++)
          obase[(size_t)rowg * D_MODEL + nb * 16 + lm] = f2bf(accO[m][nb][r] * inv);
      }
  }
}

// ------------------------------ launch ------------------------------
extern "C" void kernel_launch(void* const* d_in, const int* in_sizes, int n_in,
                              void* d_out, int out_size, void* d_ws, size_t ws_size,
                              hipStream_t stream) {
  const float* x = (const float*)d_in[0];
  const float* Wq = (const float*)d_in[1];
  const float* bq = (const float*)d_in[2];
  const float* Wk = (const float*)d_in[3];
  const float* bk = (const float*)d_in[4];
  const float* Wv = (const float*)d_in[5];
  const float* bv = (const float*)d_in[6];
  const float* Wo = (const float*)d_in[7];
  const float* bo = (const float*)d_in[8];
  const float* ln1g = (const float*)d_in[9];
  const float* ln1b = (const float*)d_in[10];
  const float* ln2g = (const float*)d_in[11];
  const float* ln2b = (const float*)d_in[12];
  const float* W1 = (const float*)d_in[13];
  const float* b1 = (const float*)d_in[14];
  const float* W2 = (const float*)d_in[15];
  const float* b2 = (const float*)d_in[16];
  float* out = (float*)d_out;

  // ---- workspace layout (~104 MB) ----
  short* wqkv_t = (short*)d_ws;                     // [3072][1024]
  short* wo_t = wqkv_t + 3072 * 1024;               // [1024][1024]
  short* w1_t = wo_t + 1024 * 1024;                 // [4096][1024]
  short* w2_t = w1_t + 4096 * 1024;                 // [1024][4096]
  float* bqkv = (float*)(w2_t + 1024 * 4096);       // [3072]
  short* h_bf = (short*)(bqkv + 3072);              // [8192][1024]
  short* qkvb = h_bf + (size_t)NTOK * D_MODEL;      // [8192][3072]
  short* vtg = qkvb + (size_t)NTOK * 3072;          // [64][64][2048]
  short* ffn1 = qkvb;  // overlay: qkvb+vtg = exactly 8192*4096 shorts

  wconvert_all<<<3072, 256, 0, stream>>>(Wq, Wk, Wv, Wo, W1, W2, wqkv_t, wo_t,
                                         w1_t, w2_t);
  hipMemcpyAsync(bqkv, bq, 1024 * sizeof(float), hipMemcpyDeviceToDevice, stream);
  hipMemcpyAsync(bqkv + 1024, bk, 1024 * sizeof(float), hipMemcpyDeviceToDevice, stream);
  hipMemcpyAsync(bqkv + 2048, bv, 1024 * sizeof(float), hipMemcpyDeviceToDevice, stream);

  ln_kernel<<<NTOK, 256, 0, stream>>>(x, ln1g, ln1b, h_bf);

  gemm_bt<0><<<dim3(24, 64), 256, 0, stream>>>(h_bf, wqkv_t, bqkv, nullptr, nullptr,
                                               qkvb, NTOK, 3072, 1024);

  vtrans<<<dim3(SS / 64, 64), 256, 0, stream>>>(qkvb, vtg);

  attn_kernel<<<dim3(64, 8), 256, 0, stream>>>(qkvb, vtg, h_bf);

  gemm_bt<1><<<dim3(8, 64), 256, 0, stream>>>(h_bf, wo_t, bo, x, out, nullptr,
                                              NTOK, 1024, 1024);

  ln_kernel<<<NTOK, 256, 0, stream>>>(out, ln2g, ln2b, h_bf);

  gemm_bt<2><<<dim3(32, 64), 256, 0, stream>>>(h_bf, w1_t, b1, nullptr, nullptr,
                                               ffn1, NTOK, 4096, 1024);

  gemm_bt<1><<<dim3(8, 64), 256, 0, stream>>>(ffn1, w2_t, b2, out, out, nullptr,
                                              NTOK, 1024, 4096);
}

// Round 5
// 478.872 us; speedup vs baseline: 1.8729x; 1.2160x over previous
//
#include <hip/hip_runtime.h>
#include <hip/hip_bf16.h>
#include <math.h>

typedef __attribute__((ext_vector_type(8))) short short8;
typedef __attribute__((ext_vector_type(4))) float floatx4;
typedef __attribute__((ext_vector_type(4))) short short4v;

#define D_MODEL 1024
#define N_HEADS 16
#define DK 64
#define D_FF 4096
#define BB 4
#define SS 2048
#define NTOK (BB * SS) /* 8192 */
#define LN_EPS 1e-5f
#define SCL 0.18033688011112042f /* 0.125 * log2(e) */

static __device__ __forceinline__ short f2bf(float f) {
  union { float f; unsigned int u; } v;
  v.f = f;
  unsigned int u = v.u;
  unsigned int r = u + 0x7fffu + ((u >> 16) & 1u); // round-to-nearest-even
  return (short)(r >> 16);
}

#define GLL16(g, l)                                                            \
  __builtin_amdgcn_global_load_lds(                                            \
      (const __attribute__((address_space(1))) void*)(g),                      \
      (__attribute__((address_space(3))) void*)(l), 16, 0, 0)

// ---------------- LayerNorm: fp32 row -> bf16 row ----------------
__global__ __launch_bounds__(256) void ln_kernel(const float* __restrict__ x,
                                                 const float* __restrict__ g,
                                                 const float* __restrict__ b,
                                                 short* __restrict__ out) {
  int row = blockIdx.x;
  int t = threadIdx.x;
  const float4* rp = (const float4*)(x + (size_t)row * D_MODEL);
  float4 v = rp[t];
  float s = v.x + v.y + v.z + v.w;
  float ss = v.x * v.x + v.y * v.y + v.z * v.z + v.w * v.w;
#pragma unroll
  for (int off = 32; off >= 1; off >>= 1) {
    s += __shfl_xor(s, off, 64);
    ss += __shfl_xor(ss, off, 64);
  }
  __shared__ float red[8];
  int wv = t >> 6;
  if ((t & 63) == 0) { red[wv] = s; red[wv + 4] = ss; }
  __syncthreads();
  s = red[0] + red[1] + red[2] + red[3];
  ss = red[4] + red[5] + red[6] + red[7];
  float mu = s * (1.0f / D_MODEL);
  float var = ss * (1.0f / D_MODEL) - mu * mu;
  float rstd = rsqrtf(var + LN_EPS);
  float4 gv = ((const float4*)g)[t];
  float4 bv = ((const float4*)b)[t];
  short4v o;
  o.x = f2bf((v.x - mu) * rstd * gv.x + bv.x);
  o.y = f2bf((v.y - mu) * rstd * gv.y + bv.y);
  o.z = f2bf((v.z - mu) * rstd * gv.z + bv.z);
  o.w = f2bf((v.w - mu) * rstd * gv.w + bv.w);
  *(short4v*)(out + (size_t)row * D_MODEL + t * 4) = o;
}

// ---- Merged weight convert+transpose + bias concat: one launch ----
// blocks 0..1023: Wq/Wk/Wv/Wo; 1024..2047: W1; 2048..3071: W2; 3072: biases
__global__ __launch_bounds__(256) void wconvert_all(
    const float* __restrict__ Wq, const float* __restrict__ Wk,
    const float* __restrict__ Wv, const float* __restrict__ Wo,
    const float* __restrict__ W1, const float* __restrict__ W2,
    const float* __restrict__ bq, const float* __restrict__ bk,
    const float* __restrict__ bv,
    short* __restrict__ wqkv_t, short* __restrict__ wo_t,
    short* __restrict__ w1_t, short* __restrict__ w2_t,
    float* __restrict__ bqkv) {
  __shared__ float tile[64][65];
  int id = blockIdx.x;
  int t = threadIdx.x;
  if (id == 3072) {
    for (int i = t; i < 1024; i += 256) {
      bqkv[i] = bq[i];
      bqkv[1024 + i] = bk[i];
      bqkv[2048 + i] = bv[i];
    }
    return;
  }
  const float* W;
  short* Wt;
  int K, N, tid;
  if (id < 1024) {
    int wsel = id >> 8;
    tid = id & 255;
    K = 1024; N = 1024;
    W = wsel == 0 ? Wq : wsel == 1 ? Wk : wsel == 2 ? Wv : Wo;
    Wt = wsel < 3 ? wqkv_t + (size_t)wsel * 1024 * 1024 : wo_t;
  } else if (id < 2048) {
    tid = id - 1024; K = 1024; N = 4096; W = W1; Wt = w1_t;
  } else {
    tid = id - 2048; K = 4096; N = 1024; W = W2; Wt = w2_t;
  }
  int ntn = N >> 6;
  int n0 = (tid % ntn) * 64, k0 = (tid / ntn) * 64;
  int c = t & 63, r0 = t >> 6;
#pragma unroll
  for (int i = 0; i < 16; i++) {
    int r = r0 + i * 4;
    tile[r][c] = W[(size_t)(k0 + r) * N + n0 + c];
  }
  __syncthreads();
#pragma unroll
  for (int i = 0; i < 16; i++) {
    int r = r0 + i * 4;
    Wt[(size_t)(n0 + r) * K + k0 + c] = f2bf(tile[c][r]);
  }
}

// ---------------- GEMM: C[M,N] = A[M,K](bf16) x Bt[N,K](bf16) + bias -------------
// BK=64: LDS rows are 128 B (all 32 banks) + XOR-8 chunk swizzle -> conflict-free
// ds_read_b128; barriers halved vs BK=32. 32 KB LDS.
// MODE 0: +bias -> bf16 out; MODE 1: +bias +res(fp32) -> fp32 out;
// MODE 2: +bias, tanh-form GELU -> bf16 out
template <int MODE>
__global__ __launch_bounds__(256, 4) void gemm_bt(const short* __restrict__ A,
                                                  const short* __restrict__ Bt,
                                                  const float* __restrict__ bias,
                                                  const float* __restrict__ res,
                                                  float* __restrict__ outf,
                                                  short* __restrict__ outb,
                                                  int M, int N, int K) {
  __shared__ short As[128 * 64];
  __shared__ short Bs[128 * 64];
  int t = threadIdx.x;
  int w = t >> 6, l = t & 63;
  int lm = l & 15, lq = l >> 4;
  int m0 = blockIdx.y * 128, n0 = blockIdx.x * 128;
  floatx4 acc[4][4] = {};
  int l3 = l >> 3;
  int c7 = ((l & 7) ^ l3) * 8;  // swizzled source chunk offset (shorts)
  const short* aA = A + (size_t)(m0 + w * 8 + l3) * K + c7;
  const short* aB = Bt + (size_t)(n0 + w * 8 + l3) * K + c7;
  int wm = (w & 1) * 64, wn = (w >> 1) * 64;
  int sw = lm & 7;

  for (int kt = 0; kt < K; kt += 64) {
#pragma unroll
    for (int j = 0; j < 4; j++) {
      GLL16(aA + (size_t)(j * 32) * K, As + (j * 32 + w * 8) * 64);
      GLL16(aB + (size_t)(j * 32) * K, Bs + (j * 32 + w * 8) * 64);
    }
    aA += 64;
    aB += 64;
    __syncthreads();
#pragma unroll
    for (int kk = 0; kk < 2; kk++) {
      int rdoff = ((kk * 4 + lq) ^ sw) * 8;
      short8 af[4], bfr[4];
#pragma unroll
      for (int mi = 0; mi < 4; mi++)
        af[mi] = *(const short8*)&As[(wm + mi * 16 + lm) * 64 + rdoff];
#pragma unroll
      for (int ni = 0; ni < 4; ni++)
        bfr[ni] = *(const short8*)&Bs[(wn + ni * 16 + lm) * 64 + rdoff];
#pragma unroll
      for (int mi = 0; mi < 4; mi++)
#pragma unroll
        for (int ni = 0; ni < 4; ni++)
          acc[mi][ni] = __builtin_amdgcn_mfma_f32_16x16x32_bf16(af[mi], bfr[ni],
                                                                acc[mi][ni], 0, 0, 0);
    }
    __syncthreads();
  }

#pragma unroll
  for (int mi = 0; mi < 4; mi++) {
#pragma unroll
    for (int ni = 0; ni < 4; ni++) {
      int col = n0 + wn + ni * 16 + lm;
      float bcol = bias[col];
#pragma unroll
      for (int r = 0; r < 4; r++) {
        int row = m0 + wm + mi * 16 + lq * 4 + r;
        float v = acc[mi][ni][r] + bcol;
        size_t idx = (size_t)row * N + col;
        if (MODE == 0) {
          outb[idx] = f2bf(v);
        } else if (MODE == 1) {
          outf[idx] = v + res[idx];
        } else {
          // gelu = v * sigmoid(2u), u = 0.79788456(v + 0.044715 v^3)
          // e = exp2(2u * log2 e) = exp2(2.3022652 * (v + 0.044715 v^3))
          float vc = v + 0.044715f * v * v * v;
          float e = __builtin_amdgcn_exp2f(2.302265246314f * vc);
          float ge = v * e * __builtin_amdgcn_rcpf(e + 1.0f);
          outb[idx] = f2bf(ge);
        }
      }
    }
  }
}

// ------------- V transpose prepass: qkv v-cols -> vt[bh][d][s] -------------
__global__ __launch_bounds__(256) void vtrans(const short* __restrict__ qkv,
                                              short* __restrict__ vt) {
  __shared__ short Ls[64][72];
  int t = threadIdx.x;
  int s0 = blockIdx.x * 64;
  int bh = blockIdx.y;
  int b = bh >> 4, h = bh & 15;
  const short* vsrc = qkv + (size_t)b * SS * 3072 + 2048 + h * 64;
#pragma unroll
  for (int it = 0; it < 2; it++) {
    int idx = it * 256 + t;
    int sr = idx >> 3, ch = idx & 7;
    *(short8*)&Ls[sr][ch * 8] =
        *(const short8*)&vsrc[(size_t)(s0 + sr) * 3072 + ch * 8];
  }
  __syncthreads();
  int d = t >> 2, sb = (t & 3) * 16;
  short tmp[16];
#pragma unroll
  for (int j = 0; j < 16; j++) tmp[j] = Ls[sb + j][d];
  short8* dst = (short8*)&vt[(size_t)bh * DK * SS + (size_t)d * SS + s0 + sb];
  dst[0] = *(short8*)&tmp[0];
  dst[1] = *(short8*)&tmp[8];
}

// ------- Flash attention (causal): no-max softmax, swizzled LDS -------
__global__ __launch_bounds__(256) void attn_kernel(const short* __restrict__ qkv,
                                                   const short* __restrict__ vt,
                                                   short* __restrict__ o) {
  __shared__ short Qs[128 * 64];   // 16 KB, swizzled chunks
  __shared__ short Ks[64 * 64];    // 8 KB, swizzled
  __shared__ short Vs[64 * 64];    // 8 KB, swizzled (rows=d, cols=k)
  __shared__ short Ps[128 * 72];   // 18 KB, padded stride 72
  int t = threadIdx.x, w = t >> 6, l = t & 63;
  int bh = blockIdx.x;
  int p = blockIdx.y;   // 0..7 -> q-tiles {p, 15-p}
  int b = bh >> 4, h = bh & 15;
  const short* qbase = qkv + (size_t)b * SS * 3072 + h * DK;
  const short* kbase = qbase + 1024;
  const short* vbase = vt + (size_t)bh * DK * SS;
  short* obase = o + (size_t)b * SS * D_MODEL + h * DK;
  int l7 = l & 7, l3 = l >> 3;
  int c7 = (l7 ^ l3) * 8;        // swizzled staging chunk offset (shorts)
  int lm = l & 15, lq = l >> 4;
  int swq = lm & 7;              // reader swizzle key

  for (int ph = 0; ph < 2; ph++) {
    int qi = ph ? (15 - p) : p;
    int q0 = qi * 128;
#pragma unroll
    for (int j = 0; j < 4; j++) {
      int r8 = w * 32 + j * 8;
      GLL16(qbase + (size_t)(q0 + r8 + l3) * 3072 + c7, Qs + r8 * 64);
    }
    __syncthreads();
    short8 aq[2][2];
#pragma unroll
    for (int m = 0; m < 2; m++)
#pragma unroll
      for (int hf = 0; hf < 2; hf++)
        aq[m][hf] = *(const short8*)&Qs[(w * 32 + m * 16 + lm) * 64 +
                                        ((hf * 4 + lq) ^ swq) * 8];

    floatx4 accO[2][4] = {};
    float lst[2][4] = {};
    int wrow_min = q0 + w * 32;
    int wrow_max = wrow_min + 31;
    int ntile = 2 * qi + 2;
    for (int kt = 0; kt < ntile; kt++) {
      int k0 = kt * 64;
      __syncthreads();  // prev-iter Ks/Vs reads done
#pragma unroll
      for (int j = 0; j < 2; j++) {
        int r8 = (w * 2 + j) * 8;
        GLL16(kbase + (size_t)(k0 + r8 + l3) * 3072 + c7, Ks + r8 * 64);
        GLL16(vbase + (size_t)(r8 + l3) * SS + k0 + c7, Vs + r8 * 64);
      }
      __syncthreads();  // staging visible

      if (k0 <= wrow_max) {  // wave-uniform tile skip
        floatx4 sc[2][4];
#pragma unroll
        for (int nb = 0; nb < 4; nb++) {
          short8 k0f = *(const short8*)&Ks[(nb * 16 + lm) * 64 + (lq ^ swq) * 8];
          short8 k1f =
              *(const short8*)&Ks[(nb * 16 + lm) * 64 + ((4 + lq) ^ swq) * 8];
#pragma unroll
          for (int m = 0; m < 2; m++) {
            floatx4 z = {};
            z = __builtin_amdgcn_mfma_f32_16x16x32_bf16(aq[m][0], k0f, z, 0, 0, 0);
            z = __builtin_amdgcn_mfma_f32_16x16x32_bf16(aq[m][1], k1f, z, 0, 0, 0);
            sc[m][nb] = z;
          }
        }
        if (k0 + 63 <= wrow_min) {  // fully unmasked (wave-uniform)
#pragma unroll
          for (int m = 0; m < 2; m++)
#pragma unroll
            for (int r = 0; r < 4; r++)
#pragma unroll
              for (int nb = 0; nb < 4; nb++) {
                float pv = exp2f(sc[m][nb][r] * SCL);
                sc[m][nb][r] = pv;
                lst[m][r] += pv;
              }
        } else {
#pragma unroll
          for (int m = 0; m < 2; m++)
#pragma unroll
            for (int r = 0; r < 4; r++) {
              int rowg = q0 + w * 32 + m * 16 + lq * 4 + r;
#pragma unroll
              for (int nb = 0; nb < 4; nb++) {
                int colg = k0 + nb * 16 + lm;
                float pv = (colg > rowg) ? 0.f : exp2f(sc[m][nb][r] * SCL);
                sc[m][nb][r] = pv;
                lst[m][r] += pv;
              }
            }
        }
        // ---- P: C-layout -> LDS (truncated bf16) -> A-layout ----
#pragma unroll
        for (int m = 0; m < 2; m++)
#pragma unroll
          for (int nb = 0; nb < 4; nb++)
#pragma unroll
            for (int r = 0; r < 4; r++) {
              union { float f; unsigned int u; } cv;
              cv.f = sc[m][nb][r];
              Ps[(w * 32 + m * 16 + lq * 4 + r) * 72 + nb * 16 + lm] =
                  (short)(cv.u >> 16);
            }
        short8 pa[2][2];
#pragma unroll
        for (int m = 0; m < 2; m++)
#pragma unroll
          for (int hf = 0; hf < 2; hf++)
            pa[m][hf] =
                *(const short8*)&Ps[(w * 32 + m * 16 + lm) * 72 + hf * 32 + lq * 8];
#pragma unroll
        for (int nb = 0; nb < 4; nb++) {
          short8 v0f = *(const short8*)&Vs[(nb * 16 + lm) * 64 + (lq ^ swq) * 8];
          short8 v1f =
              *(const short8*)&Vs[(nb * 16 + lm) * 64 + ((4 + lq) ^ swq) * 8];
#pragma unroll
          for (int m = 0; m < 2; m++) {
            accO[m][nb] = __builtin_amdgcn_mfma_f32_16x16x32_bf16(pa[m][0], v0f,
                                                                  accO[m][nb], 0, 0, 0);
            accO[m][nb] = __builtin_amdgcn_mfma_f32_16x16x32_bf16(pa[m][1], v1f,
                                                                  accO[m][nb], 0, 0, 0);
          }
        }
      }
    }
#pragma unroll
    for (int m = 0; m < 2; m++)
#pragma unroll
      for (int r = 0; r < 4; r++) {
        float s = lst[m][r];
        s += __shfl_xor(s, 1, 64);
        s += __shfl_xor(s, 2, 64);
        s += __shfl_xor(s, 4, 64);
        s += __shfl_xor(s, 8, 64);
        float inv = 1.0f / s;
        int rowg = q0 + w * 32 + m * 16 + lq * 4 + r;
#pragma unroll
        for (int nb = 0; nb < 4; nb++)
          obase[(size_t)rowg * D_MODEL + nb * 16 + lm] = f2bf(accO[m][nb][r] * inv);
      }
  }
}

// ------------------------------ launch ------------------------------
extern "C" void kernel_launch(void* const* d_in, const int* in_sizes, int n_in,
                              void* d_out, int out_size, void* d_ws, size_t ws_size,
                              hipStream_t stream) {
  const float* x = (const float*)d_in[0];
  const float* Wq = (const float*)d_in[1];
  const float* bq = (const float*)d_in[2];
  const float* Wk = (const float*)d_in[3];
  const float* bk = (const float*)d_in[4];
  const float* Wv = (const float*)d_in[5];
  const float* bv = (const float*)d_in[6];
  const float* Wo = (const float*)d_in[7];
  const float* bo = (const float*)d_in[8];
  const float* ln1g = (const float*)d_in[9];
  const float* ln1b = (const float*)d_in[10];
  const float* ln2g = (const float*)d_in[11];
  const float* ln2b = (const float*)d_in[12];
  const float* W1 = (const float*)d_in[13];
  const float* b1 = (const float*)d_in[14];
  const float* W2 = (const float*)d_in[15];
  const float* b2 = (const float*)d_in[16];
  float* out = (float*)d_out;

  // ---- workspace layout (~104 MB) ----
  short* wqkv_t = (short*)d_ws;                     // [3072][1024]
  short* wo_t = wqkv_t + 3072 * 1024;               // [1024][1024]
  short* w1_t = wo_t + 1024 * 1024;                 // [4096][1024]
  short* w2_t = w1_t + 4096 * 1024;                 // [1024][4096]
  float* bqkv = (float*)(w2_t + 1024 * 4096);       // [3072]
  short* h_bf = (short*)(bqkv + 3072);              // [8192][1024]
  short* qkvb = h_bf + (size_t)NTOK * D_MODEL;      // [8192][3072]
  short* vtg = qkvb + (size_t)NTOK * 3072;          // [64][64][2048]
  short* ffn1 = qkvb;  // overlay: qkvb+vtg = exactly 8192*4096 shorts

  wconvert_all<<<3073, 256, 0, stream>>>(Wq, Wk, Wv, Wo, W1, W2, bq, bk, bv,
                                         wqkv_t, wo_t, w1_t, w2_t, bqkv);

  ln_kernel<<<NTOK, 256, 0, stream>>>(x, ln1g, ln1b, h_bf);

  gemm_bt<0><<<dim3(24, 64), 256, 0, stream>>>(h_bf, wqkv_t, bqkv, nullptr, nullptr,
                                               qkvb, NTOK, 3072, 1024);

  vtrans<<<dim3(SS / 64, 64), 256, 0, stream>>>(qkvb, vtg);

  attn_kernel<<<dim3(64, 8), 256, 0, stream>>>(qkvb, vtg, h_bf);

  gemm_bt<1><<<dim3(8, 64), 256, 0, stream>>>(h_bf, wo_t, bo, x, out, nullptr,
                                              NTOK, 1024, 1024);

  ln_kernel<<<NTOK, 256, 0, stream>>>(out, ln2g, ln2b, h_bf);

  gemm_bt<2><<<dim3(32, 64), 256, 0, stream>>>(h_bf, w1_t, b1, nullptr, nullptr,
                                               ffn1, NTOK, 4096, 1024);

  gemm_bt<1><<<dim3(8, 64), 256, 0, stream>>>(ffn1, w2_t, b2, out, out, nullptr,
                                              NTOK, 1024, 4096);
}